// Round 4
// baseline (25.772 us; speedup 1.0000x reference)
//
#include <hip/hip_runtime.h>

// out[b,k] = tanh( sum_{m in segment k} x[b,m] * w[m] ),  seg_ids sorted.
//
// R4: CSR build via O(M) boundary scatter (unchanged). Main kernel now uses
// single-wave blocks (TPB=64): 64 segments per block, ~1024-float contiguous
// m-range staged through 5 KB LDS. 32 independent waves/CU with no cross-wave
// barriers -> load/reduce phases of different waves interleave, keeping HBM
// saturated (fixes the phase-alignment bubble of the 256-thread version).

#define TPB 64                // threads per block == segments per block
#define CH  1280              // LDS chunk (floats) = 5 KB -> 32 blocks/CU
#define VPT (CH / TPB / 4)    // float4 loads per thread per chunk = 5

__global__ void build_seg_ptr_scatter(const int* __restrict__ seg_ids,
                                      int* __restrict__ seg_ptr,
                                      int M, int K) {
    int m = blockIdx.x * blockDim.x + threadIdx.x;
    if (m >= M) return;
    int a  = seg_ids[m];
    int nb = (m + 1 < M) ? seg_ids[m + 1] : K;
    if (m == 0) {
        for (int k = 0; k <= a; ++k) seg_ptr[k] = 0;
    }
    for (int k = a + 1; k <= nb; ++k) seg_ptr[k] = m + 1;
}

__global__ __launch_bounds__(TPB) void seg_reduce_tanh(
        const float* __restrict__ x,
        const float* __restrict__ w,
        const int* __restrict__ seg_ptr,
        float* __restrict__ out,
        int M, int K) {
    __shared__ float prod[CH];

    const int t  = threadIdx.x;
    const int k0 = blockIdx.x * TPB;
    const int b  = blockIdx.y;
    const float* __restrict__ xb = x + (size_t)b * (size_t)M;

    const int s    = seg_ptr[k0];          // block-uniform
    const int e    = seg_ptr[k0 + TPB];    // block-uniform
    const int base = s & ~3;               // 16B-aligned window start
    const int a_t  = seg_ptr[k0 + t];      // this thread's segment [a_t, b_t)
    const int b_t  = seg_ptr[k0 + t + 1];

    float sum = 0.0f;
    for (int c = base; c < e; c += CH) {   // normally 1 trip (CH = mean+8sigma)
        const float4* __restrict__ x4 = reinterpret_cast<const float4*>(xb + c);
        const float4* __restrict__ w4 = reinterpret_cast<const float4*>(w + c);
        float4* __restrict__ p4 = reinterpret_cast<float4*>(prod);
        // ---- cooperative float4 load + multiply into LDS ----
        #pragma unroll
        for (int j = 0; j < VPT; ++j) {
            int idx = t + j * TPB;         // float4 index within chunk
            int mm  = c + idx * 4;         // float index
            float4 v = make_float4(0.f, 0.f, 0.f, 0.f);
            if (mm < e) {                  // exact-range guard (mm%4==0, M%4==0)
                float4 xv = x4[idx];
                float4 wv = w4[idx];
                v.x = xv.x * wv.x; v.y = xv.y * wv.y;
                v.z = xv.z * wv.z; v.w = xv.w * wv.w;
            }
            p4[idx] = v;                   // ds_write_b128, conflict-free
        }
        __syncthreads();                   // 1-wave block: just a waitcnt
        // ---- per-thread serial reduce of own segment from LDS ----
        int lo = max(a_t, c);
        int hi = min(b_t, c + CH);
        for (int m = lo; m < hi; ++m) sum += prod[m - c];
        __syncthreads();
    }
    out[(size_t)b * (size_t)K + k0 + t] = tanhf(sum);
}

extern "C" void kernel_launch(void* const* d_in, const int* in_sizes, int n_in,
                              void* d_out, int out_size, void* d_ws, size_t ws_size,
                              hipStream_t stream) {
    const float* x       = (const float*)d_in[0];
    const float* w       = (const float*)d_in[1];
    const int*   seg_ids = (const int*)d_in[2];
    float* out = (float*)d_out;

    const int M = in_sizes[1];           // 65536 (w length)
    const int B = in_sizes[0] / M;       // 256
    const int K = out_size / B;          // 4096

    int* seg_ptr = (int*)d_ws;           // K+1 ints in workspace

    build_seg_ptr_scatter<<<(M + 255) / 256, 256, 0, stream>>>(seg_ids, seg_ptr, M, K);

    dim3 grid(K / TPB, B);               // (64, 256) = 16384 blocks
    seg_reduce_tanh<<<grid, TPB, 0, stream>>>(x, w, seg_ptr, out, M, K);
}